// Round 1
// baseline (275.343 us; speedup 1.0000x reference)
//
#include <hip/hip_runtime.h>
#include <math.h>

// Problem constants (E zonotope rows, content = C*H*W)
#define EROWS 64
#define NCOL  8192                 // 8*32*32
#define TAIL_OFF (EROWS * NCOL)    // tail starts after head(1) + body(63) rows

// Kernel 1: per-column err reduction, head row, body rows, and per-column
// scatter inputs (val = delta/2, flag = cross) into workspace.
__global__ void headbody_kernel(const float* __restrict__ x,
                                float* __restrict__ out,
                                float* __restrict__ val,
                                int* __restrict__ flag) {
    int k = blockIdx.x * blockDim.x + threadIdx.x;
    if (k >= NCOL) return;

    float err = 0.f;
    for (int e = 1; e < EROWS; ++e)
        err += fabsf(x[e * NCOL + k]);

    float x0    = x[k];
    float upper = x0 + err;
    float lower = x0 - err;

    float cross  = (lower * upper < 0.f) ? 1.f : 0.f;
    float nonneg = (lower >= 0.f) ? 1.f : 0.f;

    // lam = nonneg + cross*upper/(upper-lower); NaN -> 0.5 (IEEE semantics,
    // matches jnp.where(isnan(lam), 0.5, lam)). Only matters when cross==0,
    // where lam is output-neutral, but keep it faithful.
    float lam = nonneg + cross * upper / (upper - lower);
    if (isnan(lam)) lam = 0.5f;

    float delta = fmaxf(-lam * lower, (1.f - lam) * upper);

    // head (new center)
    out[k] = (delta * 0.5f + lam * x0) * cross + x0 * nonneg;

    float scale = lam * cross + nonneg;
    val[k]  = delta * 0.5f;
    flag[k] = (cross > 0.f) ? 1 : 0;

    // body: scaled old error terms (x re-read; 2 MB, L2-resident)
    for (int e = 1; e < EROWS; ++e)
        out[e * NCOL + k] = x[e * NCOL + k] * scale;
}

// Kernel 2: single-block exclusive prefix sum over cross flags (stream
// compaction) + scatter of val into the (already zeroed) tail region.
// rows[k] = (#crossing among columns < k); max row = count-1 <= NCOL-1,
// so the reference's clip is a no-op for crossing columns, and
// non-crossing columns write 0 onto zeros (skipped).
__global__ void scatter_kernel(const float* __restrict__ val,
                               const int* __restrict__ flag,
                               float* __restrict__ out) {
    const int t = threadIdx.x;            // 1024 threads
    const int PER = NCOL / 1024;          // 8 consecutive columns per thread

    int f[PER];
    int s = 0;
    for (int j = 0; j < PER; ++j) {
        f[j] = flag[t * PER + j];
        s += f[j];
    }

    __shared__ int sh[1024];
    sh[t] = s;
    __syncthreads();

    // Hillis–Steele inclusive scan over per-thread sums
    for (int off = 1; off < 1024; off <<= 1) {
        int v = (t >= off) ? sh[t - off] : 0;
        __syncthreads();
        sh[t] += v;
        __syncthreads();
    }
    int running = (t == 0) ? 0 : sh[t - 1];   // exclusive base

    for (int j = 0; j < PER; ++j) {
        int k = t * PER + j;
        if (f[j]) {
            out[TAIL_OFF + (size_t)running * NCOL + k] = val[k];
            ++running;
        }
    }
}

extern "C" void kernel_launch(void* const* d_in, const int* in_sizes, int n_in,
                              void* d_out, int out_size, void* d_ws, size_t ws_size,
                              hipStream_t stream) {
    const float* x = (const float*)d_in[0];
    float* out = (float*)d_out;

    float* val  = (float*)d_ws;
    int*   flag = (int*)((char*)d_ws + NCOL * sizeof(float));

    // Zero the whole output (d_out is poisoned 0xAA before every launch).
    // Tail region needs zeros; head/body get overwritten stream-ordered.
    hipMemsetAsync(d_out, 0, (size_t)out_size * sizeof(float), stream);

    headbody_kernel<<<NCOL / 256, 256, 0, stream>>>(x, out, val, flag);
    scatter_kernel<<<1, 1024, 0, stream>>>(val, flag, out);
}

// Round 2
// 271.852 us; speedup vs baseline: 1.0128x; 1.0128x over previous
//
#include <hip/hip_runtime.h>
#include <math.h>

// Problem constants (E zonotope rows, content = C*H*W)
#define EROWS 64
#define NCOL  8192                   // 8*32*32
#define TAIL_OFF (EROWS * NCOL)      // tail starts after head(1)+body(63) rows
#define TAIL_F4 (NCOL * NCOL / 4)    // tail size in float4 units (16,777,216)
#define ROW_F4  (NCOL / 4)           // float4 per row (2048)

// ws layout (bytes):
//   val     float[NCOL]  @ 0
//   flag    int[NCOL]    @ 32768
//   colof   int[NCOL]    @ 65536
//   tailval float[NCOL]  @ 98304
//   count   int          @ 131072
#define WS_VAL(ws)     ((float*)(ws))
#define WS_FLAG(ws)    ((int*)((char*)(ws) + 32768))
#define WS_COLOF(ws)   ((int*)((char*)(ws) + 65536))
#define WS_TAILVAL(ws) ((float*)((char*)(ws) + 98304))
#define WS_COUNT(ws)   ((int*)((char*)(ws) + 131072))

// Kernel 1: per-column err reduction -> head row + body rows + (val, flag).
// Math identical (same fp32 op order) to the verified R0 kernel: absmax 0.
__global__ void headbody_kernel(const float* __restrict__ x,
                                float* __restrict__ out,
                                float* __restrict__ val,
                                int* __restrict__ flag) {
    int k = blockIdx.x * blockDim.x + threadIdx.x;
    if (k >= NCOL) return;

    float err = 0.f;
    for (int e = 1; e < EROWS; ++e)
        err += fabsf(x[e * NCOL + k]);

    float x0    = x[k];
    float upper = x0 + err;
    float lower = x0 - err;

    float cross  = (lower * upper < 0.f) ? 1.f : 0.f;
    float nonneg = (lower >= 0.f) ? 1.f : 0.f;

    float lam = nonneg + cross * upper / (upper - lower);
    if (isnan(lam)) lam = 0.5f;

    float delta = fmaxf(-lam * lower, (1.f - lam) * upper);

    out[k] = (delta * 0.5f + lam * x0) * cross + x0 * nonneg;   // head

    float scale = lam * cross + nonneg;
    val[k]  = delta * 0.5f;
    flag[k] = (cross > 0.f) ? 1 : 0;

    for (int e = 1; e < EROWS; ++e)                             // body
        out[e * NCOL + k] = x[e * NCOL + k] * scale;
}

// Kernel 2: single-block exclusive scan over cross flags; emits the INVERSE
// compaction map: colof[r] = column of the r-th crossing column,
// tailval[r] = val at that column, count = total crossings.
__global__ void scan_kernel(const float* __restrict__ val,
                            const int* __restrict__ flag,
                            int* __restrict__ colof,
                            float* __restrict__ tailval,
                            int* __restrict__ count) {
    const int t = threadIdx.x;            // 1024 threads
    const int PER = NCOL / 1024;          // 8 consecutive columns per thread

    int f[PER];
    int s = 0;
    for (int j = 0; j < PER; ++j) {
        f[j] = flag[t * PER + j];
        s += f[j];
    }

    __shared__ int sh[1024];
    sh[t] = s;
    __syncthreads();

    for (int off = 1; off < 1024; off <<= 1) {   // Hillis–Steele inclusive
        int v = (t >= off) ? sh[t - off] : 0;
        __syncthreads();
        sh[t] += v;
        __syncthreads();
    }
    int running = (t == 0) ? 0 : sh[t - 1];      // exclusive base

    for (int j = 0; j < PER; ++j) {
        int k = t * PER + j;
        if (f[j]) {
            colof[running]   = k;
            tailval[running] = val[k];
            ++running;
        }
    }
    if (t == 1023) *count = sh[1023];
}

// Kernel 3: single-pass tail writer. One float4 store per thread over the
// 256 MiB tail: zeros except the component where colof[row] falls in this
// float4. Write-BW-bound: ~4 cheap VALU ops per 16 B store.
__global__ void tail_kernel(const int* __restrict__ colof,
                            const float* __restrict__ tailval,
                            const int* __restrict__ count,
                            float* __restrict__ out) {
    int q  = blockIdx.x * blockDim.x + threadIdx.x;  // float4 index in tail
    int r  = q >> 11;                                // row (2048 f4/row)
    int c0 = (q & 2047) << 2;                        // first column of this f4

    int cnt = *count;                                // uniform -> scalar load
    // Guard: colof/tailval are garbage (poisoned ws) for r >= cnt.
    int   col = (r < cnt) ? colof[r]   : -1;
    float tv  = (r < cnt) ? tailval[r] : 0.f;

    float4 v;
    v.x = (col == c0 + 0) ? tv : 0.f;
    v.y = (col == c0 + 1) ? tv : 0.f;
    v.z = (col == c0 + 2) ? tv : 0.f;
    v.w = (col == c0 + 3) ? tv : 0.f;

    ((float4*)out)[TAIL_OFF / 4 + q] = v;
}

extern "C" void kernel_launch(void* const* d_in, const int* in_sizes, int n_in,
                              void* d_out, int out_size, void* d_ws, size_t ws_size,
                              hipStream_t stream) {
    const float* x = (const float*)d_in[0];
    float* out = (float*)d_out;

    headbody_kernel<<<NCOL / 256, 256, 0, stream>>>(x, out, WS_VAL(d_ws), WS_FLAG(d_ws));
    scan_kernel<<<1, 1024, 0, stream>>>(WS_VAL(d_ws), WS_FLAG(d_ws),
                                        WS_COLOF(d_ws), WS_TAILVAL(d_ws), WS_COUNT(d_ws));
    tail_kernel<<<TAIL_F4 / 256, 256, 0, stream>>>(WS_COLOF(d_ws), WS_TAILVAL(d_ws),
                                                   WS_COUNT(d_ws), out);
}